// Round 1
// baseline (248.848 us; speedup 1.0000x reference)
//
#include <hip/hip_runtime.h>
#include <stdint.h>

// RNN_autoreg: 2-layer LSTM (B=4096, T=60, H=128) fused into one persistent kernel.
// grid=256 blocks (1/CU), block=512 threads (8 waves), 16 batch rows/block.
// Weights held in VGPRs as bf16 MFMA B-fragments across the whole T loop.
// ws layout: [0, 63MB) = h1 history (bf16, [blk][t][16][128]); [63MB, +2KB) = W_out@W_lat fold.

typedef __bf16 bf16x8 __attribute__((ext_vector_type(8)));
typedef __bf16 bf16x4 __attribute__((ext_vector_type(4)));
typedef float  f32x4  __attribute__((ext_vector_type(4)));

#define H_BUF   0        // [16][128] bf16, XOR-swizzled (4096 B)
#define X_BUF   4096     // [16][128] bf16, XOR-swizzled (4096 B)
#define XMAIN   8192     // [16][60][4] f32 (15360 B)
#define WCOMB   23552    // [4][128] f32 (2048 B)
#define LDS_SZ  25600

__device__ __forceinline__ float sigm_(float x){
  return __builtin_amdgcn_rcpf(1.0f + __expf(-x));
}
__device__ __forceinline__ float tanh_(float x){
  float ax = __builtin_fabsf(x);
  float e  = __expf(-2.0f*ax);
  float t  = (1.0f - e) * __builtin_amdgcn_rcpf(1.0f + e);
  return __builtin_copysignf(t, x);
}
__device__ __forceinline__ bf16x8 ldw8(const float* __restrict__ p){
  float4 a = *(const float4*)p;
  float4 b = *(const float4*)(p+4);
  bf16x8 r;
  r[0]=(__bf16)a.x; r[1]=(__bf16)a.y; r[2]=(__bf16)a.z; r[3]=(__bf16)a.w;
  r[4]=(__bf16)b.x; r[5]=(__bf16)b.y; r[6]=(__bf16)b.z; r[7]=(__bf16)b.w;
  return r;
}
// B-fragment for lane: element i of frag kk = W[n][off + 32*kk + 8*gg + i]
__device__ __forceinline__ void load_wgate(bf16x8 (&dst)[8], const float* pih, const float* phh, int gg){
  #pragma unroll
  for (int kk=0;kk<4;++kk) dst[kk]   = ldw8(pih + kk*32 + gg*8);
  #pragma unroll
  for (int kk=0;kk<4;++kk) dst[4+kk] = ldw8(phh + kk*32 + gg*8);
}
__device__ __forceinline__ float dot16(bf16x8 h0, bf16x8 h1, float4 w0, float4 w1, float4 w2, float4 w3){
  float v = (float)h0[0]*w0.x + (float)h0[1]*w0.y + (float)h0[2]*w0.z + (float)h0[3]*w0.w;
  v += (float)h0[4]*w1.x + (float)h0[5]*w1.y + (float)h0[6]*w1.z + (float)h0[7]*w1.w;
  v += (float)h1[0]*w2.x + (float)h1[1]*w2.y + (float)h1[2]*w2.z + (float)h1[3]*w2.w;
  v += (float)h1[4]*w3.x + (float)h1[5]*w3.y + (float)h1[6]*w3.z + (float)h1[7]*w3.w;
  return v;
}

// Fold W_out @ W_lat -> wcomb[4][128], bcomb[4] at wcomb[512..515]
__global__ void comb_kernel(const float* __restrict__ W_lat, const float* __restrict__ b_lat,
                            const float* __restrict__ W_out, const float* __restrict__ b_out,
                            float* __restrict__ wcomb){
  int tid = threadIdx.x;
  int m = tid >> 7, k = tid & 127;
  float s = 0.f;
  for (int a=0;a<128;++a) s += W_out[m*128+a]*W_lat[a*128+k];
  wcomb[tid] = s;
  if (tid < 4){
    float sb = b_out[tid];
    for (int a=0;a<128;++a) sb += W_out[tid*128+a]*b_lat[a];
    wcomb[512+tid] = sb;
  }
}

#define MFMA_BLOCK(BUFOFF, KOFF) \
  { \
    _Pragma("unroll") \
    for (int kk=0;kk<4;++kk){ \
      uint4 q = *(const uint4*)(lds + (BUFOFF) + ((abase + 64u*(uint32_t)kk) ^ amask)); \
      bf16x8 af = __builtin_bit_cast(bf16x8, q); \
      a0 = __builtin_amdgcn_mfma_f32_16x16x32_bf16(af, wB0[kk+(KOFF)], a0, 0,0,0); \
      a1 = __builtin_amdgcn_mfma_f32_16x16x32_bf16(af, wB1[kk+(KOFF)], a1, 0,0,0); \
      a2 = __builtin_amdgcn_mfma_f32_16x16x32_bf16(af, wB2[kk+(KOFF)], a2, 0,0,0); \
      a3 = __builtin_amdgcn_mfma_f32_16x16x32_bf16(af, wB3[kk+(KOFF)], a3, 0,0,0); \
    } \
  }

__global__ __launch_bounds__(512, 2)
void lstm_fused(const float* __restrict__ xmain_g, const float* __restrict__ sfc,
                const float* __restrict__ mem_g, const float* __restrict__ hx2g,
                const float* __restrict__ cx2g,
                const float* __restrict__ Wsfc1, const float* __restrict__ bsfc1,
                const float* __restrict__ Wsfc2, const float* __restrict__ bsfc2,
                const float* __restrict__ Wih1, const float* __restrict__ Whh1,
                const float* __restrict__ bih1, const float* __restrict__ bhh1,
                const float* __restrict__ Wih2, const float* __restrict__ Whh2,
                const float* __restrict__ bih2, const float* __restrict__ bhh2,
                const float* __restrict__ Wso, const float* __restrict__ bso,
                const float* __restrict__ wcomb_ws,
                uint2* __restrict__ ws_u2, float* __restrict__ dout)
{
  __shared__ __align__(16) unsigned char lds[LDS_SZ];
  const int tid = threadIdx.x;
  const int w   = tid >> 6;        // wave 0..7
  const int l   = tid & 63;
  const int gg  = l >> 4;          // 16-lane group 0..3
  const int l16 = l & 15;
  const int blk = blockIdx.x;
  const int b0  = blk * 16;
  const int j   = (w<<4) + l16;    // hidden unit col 0..127 owned by this thread
  const uint32_t amask = (uint32_t)((l16 & 7) << 4);           // XOR swizzle for A-frag row = l16
  const uint32_t abase = (uint32_t)(l16*256 + gg*16);
  const int srow = tid >> 5;                                   // staging row 0..15
  const uint32_t stg_off = (uint32_t)(((srow*256) + (tid&31)*8) ^ ((srow&7)<<4));
  uint32_t hw_off[4];
  #pragma unroll
  for (int i=0;i<4;++i){
    int r = gg*4 + i;                                          // batch row owned (C/D layout)
    hw_off[i] = (uint32_t)((r*256 + j*2) ^ ((r&7)<<4));
  }
  const size_t ws_base = (size_t)blk * 60 * 512;

  // ---------------- phase 1 prologue ----------------
  {
    const float4* src = (const float4*)(xmain_g + (size_t)b0*240);
    float4* dst = (float4*)(lds + XMAIN);
    dst[tid] = src[tid];
    if (tid < 448) dst[tid+512] = src[tid+512];
  }
  const float* memrow = mem_g + (size_t)(b0 + srow)*7680 + (tid&31)*4;
  {
    float4 mv = *(const float4*)memrow;   // rnn1_mem[:, t=0]
    bf16x4 m4; m4[0]=(__bf16)mv.x; m4[1]=(__bf16)mv.y; m4[2]=(__bf16)mv.z; m4[3]=(__bf16)mv.w;
    *(bf16x4*)(lds + X_BUF + stg_off) = m4;
  }
  { // h1_0 = tanh(sfc @ Wsfc1^T + bsfc1)
    int c0 = (tid&31)*4;
    float4 wa = *(const float4*)(Wsfc1 + c0*3);
    float4 wb = *(const float4*)(Wsfc1 + c0*3 + 4);
    float4 wc = *(const float4*)(Wsfc1 + c0*3 + 8);
    const float* sp = sfc + (size_t)(b0+srow)*3;
    float s0 = sp[0], s1 = sp[1], s2 = sp[2];
    float4 bb = *(const float4*)(bsfc1 + c0);
    float v0 = tanh_(bb.x + s0*wa.x + s1*wa.y + s2*wa.z);
    float v1 = tanh_(bb.y + s0*wa.w + s1*wb.x + s2*wb.y);
    float v2 = tanh_(bb.z + s0*wb.z + s1*wb.w + s2*wc.x);
    float v3 = tanh_(bb.w + s0*wc.y + s1*wc.z + s2*wc.w);
    bf16x4 h4; h4[0]=(__bf16)v0; h4[1]=(__bf16)v1; h4[2]=(__bf16)v2; h4[3]=(__bf16)v3;
    *(bf16x4*)(lds + H_BUF + stg_off) = h4;
  }
  float c_[4];
  { // c1_0 = tanh(sfc @ Wsfc2^T + bsfc2), distributed register layout
    const float* wr = Wsfc2 + j*3;
    float w0_=wr[0], w1_=wr[1], w2_=wr[2];
    float bj = bsfc2[j];
    #pragma unroll
    for (int i=0;i<4;++i){
      const float* sp = sfc + (size_t)(b0 + gg*4 + i)*3;
      c_[i] = tanh_(bj + sp[0]*w0_ + sp[1]*w1_ + sp[2]*w2_);
    }
  }
  // weights: gate g gives col n = 128g + j. K 0..127 = x-operand (mem / h1), K 128..255 = h-operand
  bf16x8 wB0[8], wB1[8], wB2[8], wB3[8];
  load_wgate(wB0, Wih1 + 4 + (size_t)(0*128+j)*132, Whh1 + (size_t)(0*128+j)*128, gg);
  load_wgate(wB1, Wih1 + 4 + (size_t)(1*128+j)*132, Whh1 + (size_t)(1*128+j)*128, gg);
  load_wgate(wB2, Wih1 + 4 + (size_t)(2*128+j)*132, Whh1 + (size_t)(2*128+j)*128, gg);
  load_wgate(wB3, Wih1 + 4 + (size_t)(3*128+j)*132, Whh1 + (size_t)(3*128+j)*128, gg);
  float4 wx0 = *(const float4*)(Wih1 + (size_t)(0*128+j)*132);
  float4 wx1 = *(const float4*)(Wih1 + (size_t)(1*128+j)*132);
  float4 wx2 = *(const float4*)(Wih1 + (size_t)(2*128+j)*132);
  float4 wx3 = *(const float4*)(Wih1 + (size_t)(3*128+j)*132);
  float bias0 = bih1[0*128+j] + bhh1[0*128+j];
  float bias1 = bih1[1*128+j] + bhh1[1*128+j];
  float bias2 = bih1[2*128+j] + bhh1[2*128+j];
  float bias3 = bih1[3*128+j] + bhh1[3*128+j];
  __syncthreads();

  // ---------------- phase 1: LSTM1 over flipped inputs ----------------
  #pragma unroll 1
  for (int t=0; t<60; ++t){
    float4 pre;
    if (t < 59) pre = *(const float4*)(memrow + (size_t)(t+1)*128);  // prefetch mem[t+1]
    if (t > 0){  // write hs1[t-1] to scratch (coalesced from LDS)
      uint2 hv = *(const uint2*)(lds + H_BUF + stg_off);
      ws_u2[ws_base + (size_t)(t-1)*512 + tid] = hv;
    }
    const int tt = 59 - t;  // flipped inputs_main index
    f32x4 a0, a1, a2, a3;
    #pragma unroll
    for (int i=0;i<4;++i){
      const float4 xv = *(const float4*)(lds + XMAIN + (((gg*4+i)*60 + tt)<<4));
      a0[i] = bias0 + xv.x*wx0.x + xv.y*wx0.y + xv.z*wx0.z + xv.w*wx0.w;
      a1[i] = bias1 + xv.x*wx1.x + xv.y*wx1.y + xv.z*wx1.z + xv.w*wx1.w;
      a2[i] = bias2 + xv.x*wx2.x + xv.y*wx2.y + xv.z*wx2.z + xv.w*wx2.w;
      a3[i] = bias3 + xv.x*wx3.x + xv.y*wx3.y + xv.z*wx3.z + xv.w*wx3.w;
    }
    MFMA_BLOCK(X_BUF, 0)
    MFMA_BLOCK(H_BUF, 4)
    float hn[4];
    #pragma unroll
    for (int i=0;i<4;++i){
      float ci = sigm_(a1[i])*c_[i] + sigm_(a0[i])*tanh_(a2[i]);
      c_[i] = ci;
      hn[i] = sigm_(a3[i])*tanh_(ci);
    }
    __syncthreads();
    #pragma unroll
    for (int i=0;i<4;++i)
      *(__bf16*)(lds + H_BUF + hw_off[i]) = (__bf16)hn[i];
    if (t < 59){
      bf16x4 m4; m4[0]=(__bf16)pre.x; m4[1]=(__bf16)pre.y; m4[2]=(__bf16)pre.z; m4[3]=(__bf16)pre.w;
      *(bf16x4*)(lds + X_BUF + stg_off) = m4;
    }
    __syncthreads();
  }
  { // hs1[59]
    uint2 hv = *(const uint2*)(lds + H_BUF + stg_off);
    ws_u2[ws_base + (size_t)59*512 + tid] = hv;
  }

  // ---------------- phase transition ----------------
  // rnn1out[:,0] = hs1[59] is in H_BUF: copy to X_BUF verbatim (swizzle-preserving)
  ((uint2*)(lds + X_BUF))[tid] = ((const uint2*)(lds + H_BUF))[tid];
  __syncthreads();
  {
    float4 hv = *(const float4*)(hx2g + (size_t)(b0+srow)*128 + (tid&31)*4);
    bf16x4 h4; h4[0]=(__bf16)hv.x; h4[1]=(__bf16)hv.y; h4[2]=(__bf16)hv.z; h4[3]=(__bf16)hv.w;
    *(bf16x4*)(lds + H_BUF + stg_off) = h4;
  }
  #pragma unroll
  for (int i=0;i<4;++i) c_[i] = cx2g[(size_t)(b0 + gg*4 + i)*128 + j];
  load_wgate(wB0, Wih2 + (size_t)(0*128+j)*128, Whh2 + (size_t)(0*128+j)*128, gg);
  load_wgate(wB1, Wih2 + (size_t)(1*128+j)*128, Whh2 + (size_t)(1*128+j)*128, gg);
  load_wgate(wB2, Wih2 + (size_t)(2*128+j)*128, Whh2 + (size_t)(2*128+j)*128, gg);
  load_wgate(wB3, Wih2 + (size_t)(3*128+j)*128, Whh2 + (size_t)(3*128+j)*128, gg);
  bias0 = bih2[0*128+j] + bhh2[0*128+j];
  bias1 = bih2[1*128+j] + bhh2[1*128+j];
  bias2 = bih2[2*128+j] + bhh2[2*128+j];
  bias3 = bih2[3*128+j] + bhh2[3*128+j];
  ((float*)(lds + WCOMB))[tid] = wcomb_ws[tid];
  const float bc = wcomb_ws[512 + ((tid>>3)&3)];
  asm volatile("s_waitcnt vmcnt(0)" ::: "memory");  // drain scratch stores before phase-2 re-reads
  __syncthreads();

  // ---------------- phase 2: LSTM2 + fused output MLP ----------------
  #pragma unroll 1
  for (int t=0; t<60; ++t){
    uint2 preh;
    if (t < 59) preh = ws_u2[ws_base + (size_t)(58-t)*512 + tid];  // prefetch hs1[59-(t+1)]
    if (t > 0){  // out[t-1] = hs2[t-1] @ wcomb^T + bcomb  (hs2[t-1] is current H_BUF)
      const int oi = tid>>3;
      const int orow = oi>>2, om = oi&3;
      const uint32_t ob = (uint32_t)(orow*256 + (tid&7)*32);
      const uint32_t omk = (uint32_t)((orow&7)<<4);
      uint4 q0 = *(const uint4*)(lds + H_BUF + (ob ^ omk));
      uint4 q1 = *(const uint4*)(lds + H_BUF + ((ob+16u) ^ omk));
      bf16x8 hh0 = __builtin_bit_cast(bf16x8, q0);
      bf16x8 hh1 = __builtin_bit_cast(bf16x8, q1);
      const float4* wp = (const float4*)(lds + WCOMB + (uint32_t)(om*512 + (tid&7)*64));
      float v = dot16(hh0, hh1, wp[0], wp[1], wp[2], wp[3]);
      v += __shfl_xor(v, 4);
      v += __shfl_xor(v, 2);
      v += __shfl_xor(v, 1);
      if ((tid & 7) == 0) dout[(size_t)(b0+orow)*240 + (size_t)(t-1)*4 + om] = v + bc;
    }
    f32x4 a0 = {bias0,bias0,bias0,bias0};
    f32x4 a1 = {bias1,bias1,bias1,bias1};
    f32x4 a2 = {bias2,bias2,bias2,bias2};
    f32x4 a3 = {bias3,bias3,bias3,bias3};
    MFMA_BLOCK(X_BUF, 0)
    MFMA_BLOCK(H_BUF, 4)
    float hn[4];
    #pragma unroll
    for (int i=0;i<4;++i){
      float ci = sigm_(a1[i])*c_[i] + sigm_(a0[i])*tanh_(a2[i]);
      c_[i] = ci;
      hn[i] = sigm_(a3[i])*tanh_(ci);
    }
    __syncthreads();
    #pragma unroll
    for (int i=0;i<4;++i)
      *(__bf16*)(lds + H_BUF + hw_off[i]) = (__bf16)hn[i];
    if (t < 59)
      *(uint2*)(lds + X_BUF + stg_off) = preh;
    __syncthreads();
  }

  { // out[:,59]
    const int oi = tid>>3;
    const int orow = oi>>2, om = oi&3;
    const uint32_t ob = (uint32_t)(orow*256 + (tid&7)*32);
    const uint32_t omk = (uint32_t)((orow&7)<<4);
    uint4 q0 = *(const uint4*)(lds + H_BUF + (ob ^ omk));
    uint4 q1 = *(const uint4*)(lds + H_BUF + ((ob+16u) ^ omk));
    bf16x8 hh0 = __builtin_bit_cast(bf16x8, q0);
    bf16x8 hh1 = __builtin_bit_cast(bf16x8, q1);
    const float4* wp = (const float4*)(lds + WCOMB + (uint32_t)(om*512 + (tid&7)*64));
    float v = dot16(hh0, hh1, wp[0], wp[1], wp[2], wp[3]);
    v += __shfl_xor(v, 4); v += __shfl_xor(v, 2); v += __shfl_xor(v, 1);
    if ((tid & 7) == 0) dout[(size_t)(b0+orow)*240 + 59*4 + om] = v + bc;
  }
  if (tid < 384){ // out_sfc = hs2[59] @ Wso^T + bso
    const int oi = tid>>3;               // 0..47
    const int orow = oi/3, om = oi - 3*orow;
    const uint32_t ob = (uint32_t)(orow*256 + (tid&7)*32);
    const uint32_t omk = (uint32_t)((orow&7)<<4);
    uint4 q0 = *(const uint4*)(lds + H_BUF + (ob ^ omk));
    uint4 q1 = *(const uint4*)(lds + H_BUF + ((ob+16u) ^ omk));
    bf16x8 hh0 = __builtin_bit_cast(bf16x8, q0);
    bf16x8 hh1 = __builtin_bit_cast(bf16x8, q1);
    const float* wrow = Wso + om*128 + (tid&7)*16;
    float4 w0v = *(const float4*)(wrow);
    float4 w1v = *(const float4*)(wrow+4);
    float4 w2v = *(const float4*)(wrow+8);
    float4 w3v = *(const float4*)(wrow+12);
    float v = dot16(hh0, hh1, w0v, w1v, w2v, w3v);
    v += __shfl_xor(v, 4); v += __shfl_xor(v, 2); v += __shfl_xor(v, 1);
    if ((tid & 7) == 0) dout[983040 + (size_t)(b0+orow)*3 + om] = v + bso[om];
  }
}

extern "C" void kernel_launch(void* const* d_in, const int* in_sizes, int n_in,
                              void* d_out, int out_size, void* d_ws, size_t ws_size,
                              hipStream_t stream){
  const float* inputs_main = (const float*)d_in[0];
  const float* inputs_sfc  = (const float*)d_in[1];
  const float* rnn1_mem    = (const float*)d_in[2];
  const float* hx2  = (const float*)d_in[3];
  const float* cx2  = (const float*)d_in[4];
  const float* W_sfc1 = (const float*)d_in[5];
  const float* b_sfc1 = (const float*)d_in[6];
  const float* W_sfc2 = (const float*)d_in[7];
  const float* b_sfc2 = (const float*)d_in[8];
  const float* Wih1 = (const float*)d_in[9];
  const float* Whh1 = (const float*)d_in[10];
  const float* bih1 = (const float*)d_in[11];
  const float* bhh1 = (const float*)d_in[12];
  const float* Wih2 = (const float*)d_in[13];
  const float* Whh2 = (const float*)d_in[14];
  const float* bih2 = (const float*)d_in[15];
  const float* bhh2 = (const float*)d_in[16];
  const float* W_lat = (const float*)d_in[17];
  const float* b_lat = (const float*)d_in[18];
  const float* W_out = (const float*)d_in[19];
  const float* b_out = (const float*)d_in[20];
  const float* W_so  = (const float*)d_in[21];
  const float* b_so  = (const float*)d_in[22];
  float* out = (float*)d_out;
  // ws: [0, 62914560) h1 history bf16; then 516 floats for wcomb/bcomb
  uint2* ws_u2 = (uint2*)d_ws;
  float* wcomb = (float*)((char*)d_ws + 62914560u);

  comb_kernel<<<dim3(1), dim3(512), 0, stream>>>(W_lat, b_lat, W_out, b_out, wcomb);
  lstm_fused<<<dim3(256), dim3(512), 0, stream>>>(inputs_main, inputs_sfc, rnn1_mem, hx2, cx2,
      W_sfc1, b_sfc1, W_sfc2, b_sfc2, Wih1, Whh1, bih1, bhh1, Wih2, Whh2, bih2, bhh2,
      W_so, b_so, wcomb, ws_u2, out);
}

// Round 2
// 209.412 us; speedup vs baseline: 1.1883x; 1.1883x over previous
//
#include <hip/hip_runtime.h>
#include <stdint.h>

// RNN_autoreg: 2-layer LSTM (B=4096, T=60, H=128), one persistent kernel.
// grid=256 (1 block/CU), 512 threads (8 waves), 16 batch rows/block.
// This revision: raw s_barrier (no vmcnt drain), 1 barrier/step, double-buffered
// H/X tiles, x-input folded into MFMA K, output MLP folded into MFMA.

typedef __bf16 bf16x8 __attribute__((ext_vector_type(8)));
typedef __bf16 bf16x4 __attribute__((ext_vector_type(4)));
typedef float  f32x4  __attribute__((ext_vector_type(4)));

#define H0_OFF  0u       // H buffers: [2][16][128] bf16, XOR-swizzled (2 x 4096 B)
#define X0_OFF  8192u    // X buffers: [2][16][128] bf16, XOR-swizzled (2 x 4096 B)
#define XA_OFF  16384u   // x-input frags: [60][16] x bf16x4 (7680 B)
#define LDS_SZ  24576

__device__ __forceinline__ bf16x8 ldw8(const float* __restrict__ p){
  float4 a = *(const float4*)p;
  float4 b = *(const float4*)(p+4);
  bf16x8 r;
  r[0]=(__bf16)a.x; r[1]=(__bf16)a.y; r[2]=(__bf16)a.z; r[3]=(__bf16)a.w;
  r[4]=(__bf16)b.x; r[5]=(__bf16)b.y; r[6]=(__bf16)b.z; r[7]=(__bf16)b.w;
  return r;
}
__device__ __forceinline__ void load_wgate(bf16x8 (&dst)[8], const float* pih, const float* phh, int gg){
  #pragma unroll
  for (int kk=0;kk<4;++kk) dst[kk]   = ldw8(pih + kk*32 + gg*8);
  #pragma unroll
  for (int kk=0;kk<4;++kk) dst[4+kk] = ldw8(phh + kk*32 + gg*8);
}
// Raw barrier: LDS visibility only. Register-destined global ops stay in flight
// across it (the whole point: no per-step vmcnt(0) drain).
__device__ __forceinline__ void step_barrier(){
  asm volatile("s_waitcnt lgkmcnt(0)\n\ts_barrier" ::: "memory");
}
// LSTM pointwise, shared-rcp form: 5 exp + 3 rcp per row (vs 10 trans naive).
__device__ __forceinline__ void lstm_pw(const f32x4& a0, const f32x4& a1,
                                        const f32x4& a2, const f32x4& a3,
                                        float (&c_)[4], float (&hn)[4]){
  #pragma unroll
  for (int i=0;i<4;++i){
    float ei = __expf(-a0[i]);
    float ef = __expf(-a1[i]);
    float eg = __expf(-2.0f*__builtin_fabsf(a2[i]));
    float sf = __builtin_amdgcn_rcpf(1.0f + ef);
    float itg = __builtin_copysignf((1.0f-eg)*__builtin_amdgcn_rcpf((1.0f+ei)*(1.0f+eg)), a2[i]);
    float ci = sf*c_[i] + itg;
    float eo = __expf(-a3[i]);
    float ec = __expf(-2.0f*__builtin_fabsf(ci));
    c_[i] = ci;
    hn[i] = __builtin_copysignf((1.0f-ec)*__builtin_amdgcn_rcpf((1.0f+eo)*(1.0f+ec)), ci);
  }
}

// Fold W_out @ W_lat -> wcomb[4][128], bcomb[4] at wcomb[512..515]
__global__ void comb_kernel(const float* __restrict__ W_lat, const float* __restrict__ b_lat,
                            const float* __restrict__ W_out, const float* __restrict__ b_out,
                            float* __restrict__ wcomb){
  int tid = threadIdx.x;
  int m = tid >> 7, k = tid & 127;
  float s = 0.f;
  for (int a=0;a<128;++a) s += W_out[m*128+a]*W_lat[a*128+k];
  wcomb[tid] = s;
  if (tid < 4){
    float sb = b_out[tid];
    for (int a=0;a<128;++a) sb += W_out[tid*128+a]*b_lat[a];
    wcomb[512+tid] = sb;
  }
}

#define MFMA4(BASE, K0) \
  { _Pragma("unroll") \
    for (int kk=0;kk<4;++kk){ \
      uint4 q = *(const uint4*)(lds + (BASE) + ((abase + 64u*(uint32_t)kk) ^ amask)); \
      bf16x8 af = __builtin_bit_cast(bf16x8, q); \
      a0 = __builtin_amdgcn_mfma_f32_16x16x32_bf16(af, wB0[kk+(K0)], a0, 0,0,0); \
      a1 = __builtin_amdgcn_mfma_f32_16x16x32_bf16(af, wB1[kk+(K0)], a1, 0,0,0); \
      a2 = __builtin_amdgcn_mfma_f32_16x16x32_bf16(af, wB2[kk+(K0)], a2, 0,0,0); \
      a3 = __builtin_amdgcn_mfma_f32_16x16x32_bf16(af, wB3[kk+(K0)], a3, 0,0,0); \
    } }

#define MFMA4_OUT(BASE, K0) \
  { _Pragma("unroll") \
    for (int kk=0;kk<4;++kk){ \
      uint4 q = *(const uint4*)(lds + (BASE) + ((abase + 64u*(uint32_t)kk) ^ amask)); \
      bf16x8 af = __builtin_bit_cast(bf16x8, q); \
      a0 = __builtin_amdgcn_mfma_f32_16x16x32_bf16(af, wB0[kk+(K0)], a0, 0,0,0); \
      a1 = __builtin_amdgcn_mfma_f32_16x16x32_bf16(af, wB1[kk+(K0)], a1, 0,0,0); \
      a2 = __builtin_amdgcn_mfma_f32_16x16x32_bf16(af, wB2[kk+(K0)], a2, 0,0,0); \
      a3 = __builtin_amdgcn_mfma_f32_16x16x32_bf16(af, wB3[kk+(K0)], a3, 0,0,0); \
      ao = __builtin_amdgcn_mfma_f32_16x16x32_bf16(af, wcB[kk], ao, 0,0,0); \
    } }

__global__ __launch_bounds__(512, 2)
void lstm_fused(const float* __restrict__ xmain_g, const float* __restrict__ sfc,
                const float* __restrict__ mem_g, const float* __restrict__ hx2g,
                const float* __restrict__ cx2g,
                const float* __restrict__ Wsfc1, const float* __restrict__ bsfc1,
                const float* __restrict__ Wsfc2, const float* __restrict__ bsfc2,
                const float* __restrict__ Wih1, const float* __restrict__ Whh1,
                const float* __restrict__ bih1, const float* __restrict__ bhh1,
                const float* __restrict__ Wih2, const float* __restrict__ Whh2,
                const float* __restrict__ bih2, const float* __restrict__ bhh2,
                const float* __restrict__ Wso, const float* __restrict__ bso,
                const float* __restrict__ wcomb_ws,
                uint2* __restrict__ ws_u2, float* __restrict__ dout)
{
  __shared__ __align__(16) unsigned char lds[LDS_SZ];
  const int tid = threadIdx.x;
  const int w   = tid >> 6;        // wave 0..7
  const int l   = tid & 63;
  const int gg  = l >> 4;          // 16-lane group 0..3
  const int l16 = l & 15;
  const int blk = blockIdx.x;
  const int b0  = blk * 16;
  const int j   = (w<<4) + l16;    // hidden col 0..127 owned by this thread
  const uint32_t amask = (uint32_t)((l16 & 7) << 4);
  const uint32_t abase = (uint32_t)(l16*256 + gg*16);
  const int srow = tid >> 5;                                   // staging row 0..15
  const uint32_t stg_off = (uint32_t)(((srow*256) + (tid&31)*8) ^ ((srow&7)<<4));
  uint32_t hw_off[4];
  #pragma unroll
  for (int i=0;i<4;++i){
    int r = gg*4 + i;                                          // batch row (C/D layout)
    hw_off[i] = (uint32_t)((r*256 + j*2) ^ ((r&7)<<4));
  }
  const size_t ws_base = (size_t)blk * 60 * 512;

  // ---------------- phase 1 prologue ----------------
  // stage XA: all 60 steps of x (4 inputs) as bf16x4 frag rows
  #pragma unroll
  for (int e = tid; e < 960; e += 512){
    int t = e >> 4, row = e & 15;
    float4 xv = *(const float4*)(xmain_g + (size_t)(b0+row)*240 + t*4);
    bf16x4 b4; b4[0]=(__bf16)xv.x; b4[1]=(__bf16)xv.y; b4[2]=(__bf16)xv.z; b4[3]=(__bf16)xv.w;
    *(bf16x4*)(lds + XA_OFF + (uint32_t)e*8u) = b4;
  }
  const float* memrow = mem_g + (size_t)(b0 + srow)*7680 + (tid&31)*4;
  { // X[0] <- rnn1_mem[:, t=0]
    float4 mv = *(const float4*)memrow;
    bf16x4 m4; m4[0]=(__bf16)mv.x; m4[1]=(__bf16)mv.y; m4[2]=(__bf16)mv.z; m4[3]=(__bf16)mv.w;
    *(bf16x4*)(lds + X0_OFF + stg_off) = m4;
  }
  { // H[0] <- h1_0 = tanh(sfc @ Wsfc1^T + bsfc1)
    int c0 = (tid&31)*4;
    float4 wa = *(const float4*)(Wsfc1 + c0*3);
    float4 wb = *(const float4*)(Wsfc1 + c0*3 + 4);
    float4 wc = *(const float4*)(Wsfc1 + c0*3 + 8);
    const float* sp = sfc + (size_t)(b0+srow)*3;
    float s0 = sp[0], s1 = sp[1], s2 = sp[2];
    float4 bb = *(const float4*)(bsfc1 + c0);
    float v0 = tanhf(bb.x + s0*wa.x + s1*wa.y + s2*wa.z);
    float v1 = tanhf(bb.y + s0*wa.w + s1*wb.x + s2*wb.y);
    float v2 = tanhf(bb.z + s0*wb.z + s1*wb.w + s2*wc.x);
    float v3 = tanhf(bb.w + s0*wc.y + s1*wc.z + s2*wc.w);
    bf16x4 h4; h4[0]=(__bf16)v0; h4[1]=(__bf16)v1; h4[2]=(__bf16)v2; h4[3]=(__bf16)v3;
    *(bf16x4*)(lds + H0_OFF + stg_off) = h4;
  }
  float c_[4];
  { // c1_0 = tanh(sfc @ Wsfc2^T + bsfc2), register layout
    const float* wr = Wsfc2 + j*3;
    float w0_=wr[0], w1_=wr[1], w2_=wr[2];
    float bj = bsfc2[j];
    #pragma unroll
    for (int i=0;i<4;++i){
      const float* sp = sfc + (size_t)(b0 + gg*4 + i)*3;
      c_[i] = tanhf(bj + sp[0]*w0_ + sp[1]*w1_ + sp[2]*w2_);
    }
  }
  // weights: B-frag col j; K frags 0..3 = x-operand (mem / h1prev), 4..7 = h-operand
  bf16x8 wB0[8], wB1[8], wB2[8], wB3[8];
  load_wgate(wB0, Wih1 + 4 + (size_t)(0*128+j)*132, Whh1 + (size_t)(0*128+j)*128, gg);
  load_wgate(wB1, Wih1 + 4 + (size_t)(1*128+j)*132, Whh1 + (size_t)(1*128+j)*128, gg);
  load_wgate(wB2, Wih1 + 4 + (size_t)(2*128+j)*132, Whh1 + (size_t)(2*128+j)*128, gg);
  load_wgate(wB3, Wih1 + 4 + (size_t)(3*128+j)*132, Whh1 + (size_t)(3*128+j)*128, gg);
  // x-weight frags (K=0..3 of the 132, zero-padded to a 32-chunk)
  bf16x8 wxB0 = {}, wxB1 = {}, wxB2 = {}, wxB3 = {};
  if (gg == 0){
    float4 x0 = *(const float4*)(Wih1 + (size_t)(0*128+j)*132);
    float4 x1 = *(const float4*)(Wih1 + (size_t)(1*128+j)*132);
    float4 x2 = *(const float4*)(Wih1 + (size_t)(2*128+j)*132);
    float4 x3 = *(const float4*)(Wih1 + (size_t)(3*128+j)*132);
    wxB0[0]=(__bf16)x0.x; wxB0[1]=(__bf16)x0.y; wxB0[2]=(__bf16)x0.z; wxB0[3]=(__bf16)x0.w;
    wxB1[0]=(__bf16)x1.x; wxB1[1]=(__bf16)x1.y; wxB1[2]=(__bf16)x1.z; wxB1[3]=(__bf16)x1.w;
    wxB2[0]=(__bf16)x2.x; wxB2[1]=(__bf16)x2.y; wxB2[2]=(__bf16)x2.z; wxB2[3]=(__bf16)x2.w;
    wxB3[0]=(__bf16)x3.x; wxB3[1]=(__bf16)x3.y; wxB3[2]=(__bf16)x3.z; wxB3[3]=(__bf16)x3.w;
  }
  float bias0 = bih1[0*128+j] + bhh1[0*128+j];
  float bias1 = bih1[1*128+j] + bhh1[1*128+j];
  float bias2 = bih1[2*128+j] + bhh1[2*128+j];
  float bias3 = bih1[3*128+j] + bhh1[3*128+j];
  float4 P0 = *(const float4*)(memrow + 128);   // prefetch mem[1]
  step_barrier();

  // ---------------- phase 1: LSTM1 over flipped inputs ----------------
  #pragma unroll 1
  for (int t=0; t<60; ++t){
    const uint32_t cur = (uint32_t)(t & 1), nxt = cur ^ 1u;
    const uint32_t Hc = H0_OFF + cur*4096u, Xc = X0_OFF + cur*4096u;
    float4 P1;
    if (t+2 < 60) P1 = *(const float4*)(memrow + (size_t)(t+2)*128);
    if (t > 0){  // hs1[t-1] -> scratch (coalesced image copy)
      uint2 hv = *(const uint2*)(lds + Hc + stg_off);
      ws_u2[ws_base + (size_t)(t-1)*512 + tid] = hv;
    }
    const int tt = 59 - t;  // flipped inputs_main index
    bf16x8 xa = {};
    if (gg == 0){
      bf16x4 x4 = *(const bf16x4*)(lds + XA_OFF + (uint32_t)((tt<<4) + l16)*8u);
      xa[0]=x4[0]; xa[1]=x4[1]; xa[2]=x4[2]; xa[3]=x4[3];
    }
    f32x4 a0 = {bias0,bias0,bias0,bias0};
    f32x4 a1 = {bias1,bias1,bias1,bias1};
    f32x4 a2 = {bias2,bias2,bias2,bias2};
    f32x4 a3 = {bias3,bias3,bias3,bias3};
    a0 = __builtin_amdgcn_mfma_f32_16x16x32_bf16(xa, wxB0, a0, 0,0,0);
    a1 = __builtin_amdgcn_mfma_f32_16x16x32_bf16(xa, wxB1, a1, 0,0,0);
    a2 = __builtin_amdgcn_mfma_f32_16x16x32_bf16(xa, wxB2, a2, 0,0,0);
    a3 = __builtin_amdgcn_mfma_f32_16x16x32_bf16(xa, wxB3, a3, 0,0,0);
    MFMA4(Xc, 0)
    MFMA4(Hc, 4)
    float hn[4];
    lstm_pw(a0, a1, a2, a3, c_, hn);
    if (t < 59){ // stage X[nxt] <- mem[t+1] (prefetched last step)
      bf16x4 m4; m4[0]=(__bf16)P0.x; m4[1]=(__bf16)P0.y; m4[2]=(__bf16)P0.z; m4[3]=(__bf16)P0.w;
      *(bf16x4*)(lds + X0_OFF + nxt*4096u + stg_off) = m4;
    }
    #pragma unroll
    for (int i=0;i<4;++i)
      *(__bf16*)(lds + H0_OFF + nxt*4096u + hw_off[i]) = (__bf16)hn[i];
    P0 = P1;
    step_barrier();
  }
  // after loop: H[0] = h1(59)
  { uint2 hv = *(const uint2*)(lds + H0_OFF + stg_off);
    ws_u2[ws_base + (size_t)59*512 + tid] = hv; }
  // X[0] <- h1(59) image (rnn2 input at t=0)
  ((uint2*)(lds + X0_OFF))[tid] = ((const uint2*)(lds + H0_OFF))[tid];
  step_barrier();   // copies done before H[0] overwrite

  // ---------------- phase transition ----------------
  {
    float4 hv = *(const float4*)(hx2g + (size_t)(b0+srow)*128 + (tid&31)*4);
    bf16x4 h4; h4[0]=(__bf16)hv.x; h4[1]=(__bf16)hv.y; h4[2]=(__bf16)hv.z; h4[3]=(__bf16)hv.w;
    *(bf16x4*)(lds + H0_OFF + stg_off) = h4;
  }
  #pragma unroll
  for (int i=0;i<4;++i) c_[i] = cx2g[(size_t)(b0 + gg*4 + i)*128 + j];
  load_wgate(wB0, Wih2 + (size_t)(0*128+j)*128, Whh2 + (size_t)(0*128+j)*128, gg);
  load_wgate(wB1, Wih2 + (size_t)(1*128+j)*128, Whh2 + (size_t)(1*128+j)*128, gg);
  load_wgate(wB2, Wih2 + (size_t)(2*128+j)*128, Whh2 + (size_t)(2*128+j)*128, gg);
  load_wgate(wB3, Wih2 + (size_t)(3*128+j)*128, Whh2 + (size_t)(3*128+j)*128, gg);
  bias0 = bih2[0*128+j] + bhh2[0*128+j];
  bias1 = bih2[1*128+j] + bhh2[1*128+j];
  bias2 = bih2[2*128+j] + bhh2[2*128+j];
  bias3 = bih2[3*128+j] + bhh2[3*128+j];
  bf16x8 wcB[4];
  #pragma unroll
  for (int kk=0;kk<4;++kk){
    bf16x8 v = {};
    if (l16 < 4) v = ldw8(wcomb_ws + l16*128 + kk*32 + gg*8);
    wcB[kk] = v;
  }
  const float bc = (l16 < 4) ? wcomb_ws[512 + l16] : 0.f;
  // drain: phase-1 scratch stores must complete before phase-2 reads;
  // hx2 staging + weight loads complete before use.
  asm volatile("s_waitcnt vmcnt(0) lgkmcnt(0)" ::: "memory");
  __builtin_amdgcn_s_barrier();
  uint2 P0u = ws_u2[ws_base + (size_t)58*512 + tid];  // prefetch h1hist[58]

  // ---------------- phase 2: LSTM2 + MFMA-fused output MLP ----------------
  #pragma unroll 1
  for (int t=0; t<60; ++t){
    const uint32_t cur = (uint32_t)(t & 1), nxt = cur ^ 1u;
    const uint32_t Hc = H0_OFF + cur*4096u, Xc = X0_OFF + cur*4096u;
    uint2 P1u;
    if (t+2 < 60) P1u = ws_u2[ws_base + (size_t)(57-t)*512 + tid];
    f32x4 a0 = {bias0,bias0,bias0,bias0};
    f32x4 a1 = {bias1,bias1,bias1,bias1};
    f32x4 a2 = {bias2,bias2,bias2,bias2};
    f32x4 a3 = {bias3,bias3,bias3,bias3};
    f32x4 ao = {0.f,0.f,0.f,0.f};
    MFMA4(Xc, 0)
    MFMA4_OUT(Hc, 4)           // gates + out-tile from h2(t-1)
    float hn[4];
    lstm_pw(a0, a1, a2, a3, c_, hn);
    if (t > 0 && w == 0 && l16 < 4){  // out[t-1] = h2(t-1) @ wcomb^T + bcomb
      #pragma unroll
      for (int i=0;i<4;++i)
        dout[(size_t)(b0 + gg*4 + i)*240 + (size_t)(t-1)*4 + l16] = ao[i] + bc;
    }
    if (t < 59)
      *(uint2*)(lds + X0_OFF + nxt*4096u + stg_off) = P0u;
    #pragma unroll
    for (int i=0;i<4;++i)
      *(__bf16*)(lds + H0_OFF + nxt*4096u + hw_off[i]) = (__bf16)hn[i];
    P0u = P1u;
    step_barrier();
  }

  // ---------------- epilogue: out[59] + out_sfc from H[0] = h2(59) ----------------
  {
    bf16x8 wsB[4];
    #pragma unroll
    for (int kk=0;kk<4;++kk){
      bf16x8 v = {};
      if (l16 < 3) v = ldw8(Wso + l16*128 + kk*32 + gg*8);
      wsB[kk] = v;
    }
    f32x4 ao = {0.f,0.f,0.f,0.f};
    f32x4 as_ = {0.f,0.f,0.f,0.f};
    #pragma unroll
    for (int kk=0;kk<4;++kk){
      uint4 q = *(const uint4*)(lds + H0_OFF + ((abase + 64u*(uint32_t)kk) ^ amask));
      bf16x8 af = __builtin_bit_cast(bf16x8, q);
      ao  = __builtin_amdgcn_mfma_f32_16x16x32_bf16(af, wcB[kk], ao, 0,0,0);
      as_ = __builtin_amdgcn_mfma_f32_16x16x32_bf16(af, wsB[kk], as_, 0,0,0);
    }
    if (w == 0 && l16 < 4){
      #pragma unroll
      for (int i=0;i<4;++i)
        dout[(size_t)(b0 + gg*4 + i)*240 + 59*4 + l16] = ao[i] + bc;
    }
    if (w == 0 && l16 < 3){
      float bs = bso[l16];
      #pragma unroll
      for (int i=0;i<4;++i)
        dout[983040 + (size_t)(b0 + gg*4 + i)*3 + l16] = as_[i] + bs;
    }
  }
}

extern "C" void kernel_launch(void* const* d_in, const int* in_sizes, int n_in,
                              void* d_out, int out_size, void* d_ws, size_t ws_size,
                              hipStream_t stream){
  const float* inputs_main = (const float*)d_in[0];
  const float* inputs_sfc  = (const float*)d_in[1];
  const float* rnn1_mem    = (const float*)d_in[2];
  const float* hx2  = (const float*)d_in[3];
  const float* cx2  = (const float*)d_in[4];
  const float* W_sfc1 = (const float*)d_in[5];
  const float* b_sfc1 = (const float*)d_in[6];
  const float* W_sfc2 = (const float*)d_in[7];
  const float* b_sfc2 = (const float*)d_in[8];
  const float* Wih1 = (const float*)d_in[9];
  const float* Whh1 = (const float*)d_in[10];
  const float* bih1 = (const float*)d_in[11];
  const float* bhh1 = (const float*)d_in[12];
  const float* Wih2 = (const float*)d_in[13];
  const float* Whh2 = (const float*)d_in[14];
  const float* bih2 = (const float*)d_in[15];
  const float* bhh2 = (const float*)d_in[16];
  const float* W_lat = (const float*)d_in[17];
  const float* b_lat = (const float*)d_in[18];
  const float* W_out = (const float*)d_in[19];
  const float* b_out = (const float*)d_in[20];
  const float* W_so  = (const float*)d_in[21];
  const float* b_so  = (const float*)d_in[22];
  float* out = (float*)d_out;
  // ws: [0, 62914560) h1 history bf16 image; then 516 floats for wcomb/bcomb
  uint2* ws_u2 = (uint2*)d_ws;
  float* wcomb = (float*)((char*)d_ws + 62914560u);

  comb_kernel<<<dim3(1), dim3(512), 0, stream>>>(W_lat, b_lat, W_out, b_out, wcomb);
  lstm_fused<<<dim3(256), dim3(512), 0, stream>>>(inputs_main, inputs_sfc, rnn1_mem, hx2, cx2,
      W_sfc1, b_sfc1, W_sfc2, b_sfc2, Wih1, Whh1, bih1, bhh1, Wih2, Whh2, bih2, bhh2,
      W_so, b_so, wcomb, ws_u2, out);
}

// Round 3
// 194.182 us; speedup vs baseline: 1.2815x; 1.0784x over previous
//
#include <hip/hip_runtime.h>
#include <stdint.h>

// RNN_autoreg: 2-layer LSTM (B=4096, T=60, H=128), one persistent kernel.
// 256 blocks (1/CU), 512 threads (8 waves), 16 batch rows/block.
// This revision: h1-history LIFO kept in LDS (34 of 60 slices; slots double as
// phase-1 X staging), exp2-prescaled weights (no mul before v_exp), out-MLP
// MFMA on wave 0 only.

typedef __bf16 bf16x8 __attribute__((ext_vector_type(8)));
typedef __bf16 bf16x4 __attribute__((ext_vector_type(4)));
typedef float  f32x4  __attribute__((ext_vector_type(4)));

#define HQ      4096u
#define H0_OFF  0u        // H dbuf: 2 x 4096
#define XD_OFF  8192u     // X dbuf (early slots): 2 x 4096
#define XA_OFF  16384u    // x-input frags: [60][16] bf16x4 = 7680 B
#define HIST    24064u    // 34 slices x 4096 (slots 26..59)
#define LDS_SZ  163328
#define NWS     26        // slices 0..25 go through workspace

#define S1f (-1.4426950408889634f)   // -log2(e)   for i,f,o gates
#define S2f (-2.8853900817779268f)   // -2*log2(e) for g gate / tanh(c)

__device__ __forceinline__ bf16x8 ldw8s(const float* __restrict__ p, float s){
  float4 a = *(const float4*)p;
  float4 b = *(const float4*)(p+4);
  bf16x8 r;
  r[0]=(__bf16)(a.x*s); r[1]=(__bf16)(a.y*s); r[2]=(__bf16)(a.z*s); r[3]=(__bf16)(a.w*s);
  r[4]=(__bf16)(b.x*s); r[5]=(__bf16)(b.y*s); r[6]=(__bf16)(b.z*s); r[7]=(__bf16)(b.w*s);
  return r;
}
__device__ __forceinline__ void load_wgate(bf16x8 (&dst)[8], const float* pih, const float* phh, int gg, float s){
  #pragma unroll
  for (int kk=0;kk<4;++kk) dst[kk]   = ldw8s(pih + kk*32 + gg*8, s);
  #pragma unroll
  for (int kk=0;kk<4;++kk) dst[4+kk] = ldw8s(phh + kk*32 + gg*8, s);
}
// Raw barrier: LDS visibility only; register-destined global ops stay in flight.
__device__ __forceinline__ void step_barrier(){
  asm volatile("s_waitcnt lgkmcnt(0)\n\ts_barrier" ::: "memory");
}
// Pointwise with exp2-prescaled gates: a0=-L*i, a1=-L*f, a2=-2L*g, a3=-L*o.
__device__ __forceinline__ void lstm_pw(const f32x4& a0, const f32x4& a1,
                                        const f32x4& a2, const f32x4& a3,
                                        float (&c_)[4], float (&hn)[4]){
  #pragma unroll
  for (int i=0;i<4;++i){
    float ei = __builtin_amdgcn_exp2f(a0[i]);
    float ef = __builtin_amdgcn_exp2f(a1[i]);
    float eg = __builtin_amdgcn_exp2f(fminf(a2[i], 126.0f));  // clamp: lone NaN edge
    float eo = __builtin_amdgcn_exp2f(a3[i]);
    float sf = __builtin_amdgcn_rcpf(1.0f + ef);
    float itg = (1.0f - eg) * __builtin_amdgcn_rcpf((1.0f + ei)*(1.0f + eg));
    float ci = sf*c_[i] + itg;
    float ec = __builtin_amdgcn_exp2f(S2f*__builtin_fabsf(ci));
    float th = (1.0f - ec) * __builtin_amdgcn_rcpf((1.0f + eo)*(1.0f + ec));
    c_[i] = ci;
    hn[i] = __builtin_copysignf(th, ci);
  }
}

// Fold W_out @ W_lat -> wcomb[4][128], bcomb[4] at wcomb[512..515]
__global__ void comb_kernel(const float* __restrict__ W_lat, const float* __restrict__ b_lat,
                            const float* __restrict__ W_out, const float* __restrict__ b_out,
                            float* __restrict__ wcomb){
  int tid = threadIdx.x;
  int m = tid >> 7, k = tid & 127;
  float s = 0.f;
  for (int a=0;a<128;++a) s += W_out[m*128+a]*W_lat[a*128+k];
  wcomb[tid] = s;
  if (tid < 4){
    float sb = b_out[tid];
    for (int a=0;a<128;++a) sb += W_out[tid*128+a]*b_lat[a];
    wcomb[512+tid] = sb;
  }
}

#define MFMA4(BASE, K0) \
  { _Pragma("unroll") \
    for (int kk=0;kk<4;++kk){ \
      uint4 q = *(const uint4*)(lds + (BASE) + ((abase + 64u*(uint32_t)kk) ^ amask)); \
      bf16x8 af = __builtin_bit_cast(bf16x8, q); \
      a0 = __builtin_amdgcn_mfma_f32_16x16x32_bf16(af, wB0[kk+(K0)], a0, 0,0,0); \
      a1 = __builtin_amdgcn_mfma_f32_16x16x32_bf16(af, wB1[kk+(K0)], a1, 0,0,0); \
      a2 = __builtin_amdgcn_mfma_f32_16x16x32_bf16(af, wB2[kk+(K0)], a2, 0,0,0); \
      a3 = __builtin_amdgcn_mfma_f32_16x16x32_bf16(af, wB3[kk+(K0)], a3, 0,0,0); \
    } }

__global__ __launch_bounds__(512, 2)
void lstm_fused(const float* __restrict__ xmain_g, const float* __restrict__ sfc,
                const float* __restrict__ mem_g, const float* __restrict__ hx2g,
                const float* __restrict__ cx2g,
                const float* __restrict__ Wsfc1, const float* __restrict__ bsfc1,
                const float* __restrict__ Wsfc2, const float* __restrict__ bsfc2,
                const float* __restrict__ Wih1, const float* __restrict__ Whh1,
                const float* __restrict__ bih1, const float* __restrict__ bhh1,
                const float* __restrict__ Wih2, const float* __restrict__ Whh2,
                const float* __restrict__ bih2, const float* __restrict__ bhh2,
                const float* __restrict__ Wso, const float* __restrict__ bso,
                const float* __restrict__ wcomb_ws,
                uint2* __restrict__ ws_u2, float* __restrict__ dout)
{
  __shared__ __align__(16) unsigned char lds[LDS_SZ];
  const int tid = threadIdx.x;
  const int w   = tid >> 6;
  const int l   = tid & 63;
  const int gg  = l >> 4;
  const int l16 = l & 15;
  const int blk = blockIdx.x;
  const int b0  = blk * 16;
  const int j   = (w<<4) + l16;
  const uint32_t amask = (uint32_t)((l16 & 7) << 4);
  const uint32_t abase = (uint32_t)(l16*256 + gg*16);
  const int srow = tid >> 5;
  const uint32_t stg_off = (uint32_t)(((srow*256) + (tid&31)*8) ^ ((srow&7)<<4));
  uint32_t hw_off[4];
  #pragma unroll
  for (int i=0;i<4;++i){
    int r = gg*4 + i;
    hw_off[i] = (uint32_t)((r*256 + j*2) ^ ((r&7)<<4));
  }
  const size_t ws_base = (size_t)blk * NWS * 512;

  // ---------------- phase 1 prologue ----------------
  #pragma unroll
  for (int e = tid; e < 960; e += 512){      // XA: x inputs for all 60 steps
    int t = e >> 4, row = e & 15;
    float4 xv = *(const float4*)(xmain_g + (size_t)(b0+row)*240 + t*4);
    bf16x4 b4; b4[0]=(__bf16)xv.x; b4[1]=(__bf16)xv.y; b4[2]=(__bf16)xv.z; b4[3]=(__bf16)xv.w;
    *(bf16x4*)(lds + XA_OFF + (uint32_t)e*8u) = b4;
  }
  const float* memrow = mem_g + (size_t)(b0 + srow)*7680 + (tid&31)*4;
  { // slot 0 (mem[:,0]) -> XD[0]
    float4 mv = *(const float4*)memrow;
    bf16x4 m4; m4[0]=(__bf16)mv.x; m4[1]=(__bf16)mv.y; m4[2]=(__bf16)mv.z; m4[3]=(__bf16)mv.w;
    *(bf16x4*)(lds + XD_OFF + stg_off) = m4;
  }
  { // H[0] <- h1_0 = tanh(sfc @ Wsfc1^T + bsfc1)
    int c0 = (tid&31)*4;
    float4 wa = *(const float4*)(Wsfc1 + c0*3);
    float4 wb = *(const float4*)(Wsfc1 + c0*3 + 4);
    float4 wc = *(const float4*)(Wsfc1 + c0*3 + 8);
    const float* sp = sfc + (size_t)(b0+srow)*3;
    float s0 = sp[0], s1 = sp[1], s2 = sp[2];
    float4 bb = *(const float4*)(bsfc1 + c0);
    float v0 = tanhf(bb.x + s0*wa.x + s1*wa.y + s2*wa.z);
    float v1 = tanhf(bb.y + s0*wa.w + s1*wb.x + s2*wb.y);
    float v2 = tanhf(bb.z + s0*wb.z + s1*wb.w + s2*wc.x);
    float v3 = tanhf(bb.w + s0*wc.y + s1*wc.z + s2*wc.w);
    bf16x4 h4; h4[0]=(__bf16)v0; h4[1]=(__bf16)v1; h4[2]=(__bf16)v2; h4[3]=(__bf16)v3;
    *(bf16x4*)(lds + H0_OFF + stg_off) = h4;
  }
  float c_[4];
  {
    const float* wr = Wsfc2 + j*3;
    float w0_=wr[0], w1_=wr[1], w2_=wr[2];
    float bj = bsfc2[j];
    #pragma unroll
    for (int i=0;i<4;++i){
      const float* sp = sfc + (size_t)(b0 + gg*4 + i)*3;
      c_[i] = tanhf(bj + sp[0]*w0_ + sp[1]*w1_ + sp[2]*w2_);
    }
  }
  // weights, exp2-prescaled; K frags 0..3 = x-operand, 4..7 = h-operand
  bf16x8 wB0[8], wB1[8], wB2[8], wB3[8];
  load_wgate(wB0, Wih1 + 4 + (size_t)(0*128+j)*132, Whh1 + (size_t)(0*128+j)*128, gg, S1f);
  load_wgate(wB1, Wih1 + 4 + (size_t)(1*128+j)*132, Whh1 + (size_t)(1*128+j)*128, gg, S1f);
  load_wgate(wB2, Wih1 + 4 + (size_t)(2*128+j)*132, Whh1 + (size_t)(2*128+j)*128, gg, S2f);
  load_wgate(wB3, Wih1 + 4 + (size_t)(3*128+j)*132, Whh1 + (size_t)(3*128+j)*128, gg, S1f);
  bf16x8 wxB0 = {}, wxB1 = {}, wxB2 = {}, wxB3 = {};
  if (gg == 0){
    float4 x0 = *(const float4*)(Wih1 + (size_t)(0*128+j)*132);
    float4 x1 = *(const float4*)(Wih1 + (size_t)(1*128+j)*132);
    float4 x2 = *(const float4*)(Wih1 + (size_t)(2*128+j)*132);
    float4 x3 = *(const float4*)(Wih1 + (size_t)(3*128+j)*132);
    wxB0[0]=(__bf16)(x0.x*S1f); wxB0[1]=(__bf16)(x0.y*S1f); wxB0[2]=(__bf16)(x0.z*S1f); wxB0[3]=(__bf16)(x0.w*S1f);
    wxB1[0]=(__bf16)(x1.x*S1f); wxB1[1]=(__bf16)(x1.y*S1f); wxB1[2]=(__bf16)(x1.z*S1f); wxB1[3]=(__bf16)(x1.w*S1f);
    wxB2[0]=(__bf16)(x2.x*S2f); wxB2[1]=(__bf16)(x2.y*S2f); wxB2[2]=(__bf16)(x2.z*S2f); wxB2[3]=(__bf16)(x2.w*S2f);
    wxB3[0]=(__bf16)(x3.x*S1f); wxB3[1]=(__bf16)(x3.y*S1f); wxB3[2]=(__bf16)(x3.z*S1f); wxB3[3]=(__bf16)(x3.w*S1f);
  }
  float bias0 = (bih1[0*128+j] + bhh1[0*128+j])*S1f;
  float bias1 = (bih1[1*128+j] + bhh1[1*128+j])*S1f;
  float bias2 = (bih1[2*128+j] + bhh1[2*128+j])*S2f;
  float bias3 = (bih1[3*128+j] + bhh1[3*128+j])*S1f;
  float4 P0 = *(const float4*)(memrow + 128);   // prefetch mem[1]
  step_barrier();

  // ---------------- phase 1: LSTM1 over flipped inputs ----------------
  #pragma unroll 1
  for (int t=0; t<60; ++t){
    const uint32_t cur = (uint32_t)(t & 1), nxt = cur ^ 1u;
    const uint32_t Hc = H0_OFF + cur*HQ;
    const uint32_t xbase = (t >= NWS) ? (HIST + (uint32_t)(t-NWS)*HQ) : (XD_OFF + cur*HQ);
    float4 P1;
    if (t+2 < 60) P1 = *(const float4*)(memrow + (size_t)(t+2)*128);
    if (t > 0){   // h1(t-1): slots 0..25 -> ws, 26.. -> LDS hist
      uint2 hv = *(const uint2*)(lds + Hc + stg_off);
      if (t <= NWS) ws_u2[ws_base + (size_t)(t-1)*512 + tid] = hv;
      else *(uint2*)(lds + HIST + (uint32_t)(t-1-NWS)*HQ + stg_off) = hv;
    }
    const int tt = 59 - t;
    bf16x8 xa = {};
    if (gg == 0){
      bf16x4 x4 = *(const bf16x4*)(lds + XA_OFF + (uint32_t)((tt<<4) + l16)*8u);
      xa[0]=x4[0]; xa[1]=x4[1]; xa[2]=x4[2]; xa[3]=x4[3];
    }
    f32x4 a0 = {bias0,bias0,bias0,bias0};
    f32x4 a1 = {bias1,bias1,bias1,bias1};
    f32x4 a2 = {bias2,bias2,bias2,bias2};
    f32x4 a3 = {bias3,bias3,bias3,bias3};
    a0 = __builtin_amdgcn_mfma_f32_16x16x32_bf16(xa, wxB0, a0, 0,0,0);
    a1 = __builtin_amdgcn_mfma_f32_16x16x32_bf16(xa, wxB1, a1, 0,0,0);
    a2 = __builtin_amdgcn_mfma_f32_16x16x32_bf16(xa, wxB2, a2, 0,0,0);
    a3 = __builtin_amdgcn_mfma_f32_16x16x32_bf16(xa, wxB3, a3, 0,0,0);
    MFMA4(xbase, 0)
    MFMA4(Hc, 4)
    float hn[4];
    lstm_pw(a0, a1, a2, a3, c_, hn);
    if (t < 59){ // stage mem[t+1] into slot t+1
      const uint32_t sdst = (t+1 >= NWS) ? (HIST + (uint32_t)(t+1-NWS)*HQ) : (XD_OFF + nxt*HQ);
      bf16x4 m4; m4[0]=(__bf16)P0.x; m4[1]=(__bf16)P0.y; m4[2]=(__bf16)P0.z; m4[3]=(__bf16)P0.w;
      *(bf16x4*)(lds + sdst + stg_off) = m4;
    }
    #pragma unroll
    for (int i=0;i<4;++i)
      *(__bf16*)(lds + H0_OFF + nxt*HQ + hw_off[i]) = (__bf16)hn[i];
    P0 = P1;
    step_barrier();
  }
  { // h1(59) (in H[0]) -> HIST slot 33; then H[0] <- hx2 (same-thread chunk, ordered)
    uint2 hv = *(const uint2*)(lds + H0_OFF + stg_off);
    *(uint2*)(lds + HIST + 33u*HQ + stg_off) = hv;
    float4 h2v = *(const float4*)(hx2g + (size_t)(b0+srow)*128 + (tid&31)*4);
    bf16x4 h4; h4[0]=(__bf16)h2v.x; h4[1]=(__bf16)h2v.y; h4[2]=(__bf16)h2v.z; h4[3]=(__bf16)h2v.w;
    *(bf16x4*)(lds + H0_OFF + stg_off) = h4;
  }
  #pragma unroll
  for (int i=0;i<4;++i) c_[i] = cx2g[(size_t)(b0 + gg*4 + i)*128 + j];
  load_wgate(wB0, Wih2 + (size_t)(0*128+j)*128, Whh2 + (size_t)(0*128+j)*128, gg, S1f);
  load_wgate(wB1, Wih2 + (size_t)(1*128+j)*128, Whh2 + (size_t)(1*128+j)*128, gg, S1f);
  load_wgate(wB2, Wih2 + (size_t)(2*128+j)*128, Whh2 + (size_t)(2*128+j)*128, gg, S2f);
  load_wgate(wB3, Wih2 + (size_t)(3*128+j)*128, Whh2 + (size_t)(3*128+j)*128, gg, S1f);
  float nb0 = (bih2[0*128+j] + bhh2[0*128+j])*S1f;
  float nb1 = (bih2[1*128+j] + bhh2[1*128+j])*S1f;
  float nb2 = (bih2[2*128+j] + bhh2[2*128+j])*S2f;
  float nb3 = (bih2[3*128+j] + bhh2[3*128+j])*S1f;
  bias0=nb0; bias1=nb1; bias2=nb2; bias3=nb3;
  bf16x8 wcB[4] = {};
  if (w == 0){
    #pragma unroll
    for (int kk=0;kk<4;++kk){
      bf16x8 v = {};
      if (l16 < 4) v = ldw8s(wcomb_ws + l16*128 + kk*32 + gg*8, 1.0f);
      wcB[kk] = v;
    }
  }
  const float bc = (l16 < 4) ? wcomb_ws[512 + l16] : 0.f;
  // drain ws hist stores before phase-2 reads; settle LDS
  asm volatile("s_waitcnt vmcnt(0) lgkmcnt(0)" ::: "memory");
  __builtin_amdgcn_s_barrier();

  // ---------------- phase 2: LSTM2 + MFMA-fused output MLP ----------------
  uint2 P0u, P1u;
  #pragma unroll 1
  for (int t=0; t<60; ++t){
    const uint32_t cur = (uint32_t)(t & 1), nxt = cur ^ 1u;
    const uint32_t Hc = H0_OFF + cur*HQ;
    const int s = 59 - t;
    const uint32_t xbase = (s >= NWS) ? (HIST + (uint32_t)(s-NWS)*HQ) : (XD_OFF + cur*HQ);
    if (t >= 32 && t < 58) P1u = ws_u2[ws_base + (size_t)(57-t)*512 + tid];  // slice 57-t
    f32x4 a0 = {bias0,bias0,bias0,bias0};
    f32x4 a1 = {bias1,bias1,bias1,bias1};
    f32x4 a2 = {bias2,bias2,bias2,bias2};
    f32x4 a3 = {bias3,bias3,bias3,bias3};
    f32x4 ao = {0.f,0.f,0.f,0.f};
    MFMA4(xbase, 0)
    bf16x8 hf[4];
    #pragma unroll
    for (int kk=0;kk<4;++kk){
      uint4 q = *(const uint4*)(lds + Hc + ((abase + 64u*(uint32_t)kk) ^ amask));
      hf[kk] = __builtin_bit_cast(bf16x8, q);
    }
    #pragma unroll
    for (int kk=0;kk<4;++kk){
      a0 = __builtin_amdgcn_mfma_f32_16x16x32_bf16(hf[kk], wB0[kk+4], a0, 0,0,0);
      a1 = __builtin_amdgcn_mfma_f32_16x16x32_bf16(hf[kk], wB1[kk+4], a1, 0,0,0);
      a2 = __builtin_amdgcn_mfma_f32_16x16x32_bf16(hf[kk], wB2[kk+4], a2, 0,0,0);
      a3 = __builtin_amdgcn_mfma_f32_16x16x32_bf16(hf[kk], wB3[kk+4], a3, 0,0,0);
    }
    if (w == 0){
      #pragma unroll
      for (int kk=0;kk<4;++kk)
        ao = __builtin_amdgcn_mfma_f32_16x16x32_bf16(hf[kk], wcB[kk], ao, 0,0,0);
    }
    float hn[4];
    lstm_pw(a0, a1, a2, a3, c_, hn);
    if (t > 0 && w == 0 && l16 < 4){
      #pragma unroll
      for (int i=0;i<4;++i)
        dout[(size_t)(b0 + gg*4 + i)*240 + (size_t)(t-1)*4 + l16] = ao[i] + bc;
    }
    if (t >= 33 && t < 59)
      *(uint2*)(lds + XD_OFF + nxt*HQ + stg_off) = P0u;   // stage ws slice for t+1
    #pragma unroll
    for (int i=0;i<4;++i)
      *(__bf16*)(lds + H0_OFF + nxt*HQ + hw_off[i]) = (__bf16)hn[i];
    P0u = P1u;
    step_barrier();
  }

  // ---------------- epilogue: out[59] + out_sfc from H[0] = h2(59) ----------------
  if (w == 0){
    bf16x8 wsB[4];
    #pragma unroll
    for (int kk=0;kk<4;++kk){
      bf16x8 v = {};
      if (l16 < 3) v = ldw8s(Wso + l16*128 + kk*32 + gg*8, 1.0f);
      wsB[kk] = v;
    }
    f32x4 ao = {0.f,0.f,0.f,0.f};
    f32x4 as_ = {0.f,0.f,0.f,0.f};
    #pragma unroll
    for (int kk=0;kk<4;++kk){
      uint4 q = *(const uint4*)(lds + H0_OFF + ((abase + 64u*(uint32_t)kk) ^ amask));
      bf16x8 af = __builtin_bit_cast(bf16x8, q);
      ao  = __builtin_amdgcn_mfma_f32_16x16x32_bf16(af, wcB[kk], ao, 0,0,0);
      as_ = __builtin_amdgcn_mfma_f32_16x16x32_bf16(af, wsB[kk], as_, 0,0,0);
    }
    if (l16 < 4){
      #pragma unroll
      for (int i=0;i<4;++i)
        dout[(size_t)(b0 + gg*4 + i)*240 + 59*4 + l16] = ao[i] + bc;
    }
    if (l16 < 3){
      float bs = bso[l16];
      #pragma unroll
      for (int i=0;i<4;++i)
        dout[983040 + (size_t)(b0 + gg*4 + i)*3 + l16] = as_[i] + bs;
    }
  }
}

extern "C" void kernel_launch(void* const* d_in, const int* in_sizes, int n_in,
                              void* d_out, int out_size, void* d_ws, size_t ws_size,
                              hipStream_t stream){
  const float* inputs_main = (const float*)d_in[0];
  const float* inputs_sfc  = (const float*)d_in[1];
  const float* rnn1_mem    = (const float*)d_in[2];
  const float* hx2  = (const float*)d_in[3];
  const float* cx2  = (const float*)d_in[4];
  const float* W_sfc1 = (const float*)d_in[5];
  const float* b_sfc1 = (const float*)d_in[6];
  const float* W_sfc2 = (const float*)d_in[7];
  const float* b_sfc2 = (const float*)d_in[8];
  const float* Wih1 = (const float*)d_in[9];
  const float* Whh1 = (const float*)d_in[10];
  const float* bih1 = (const float*)d_in[11];
  const float* bhh1 = (const float*)d_in[12];
  const float* Wih2 = (const float*)d_in[13];
  const float* Whh2 = (const float*)d_in[14];
  const float* bih2 = (const float*)d_in[15];
  const float* bhh2 = (const float*)d_in[16];
  const float* W_lat = (const float*)d_in[17];
  const float* b_lat = (const float*)d_in[18];
  const float* W_out = (const float*)d_in[19];
  const float* b_out = (const float*)d_in[20];
  const float* W_so  = (const float*)d_in[21];
  const float* b_so  = (const float*)d_in[22];
  float* out = (float*)d_out;
  // ws: [0, 26*512*8*256) h1-history slices 0..25 (swizzled image chunks);
  //     wcomb at byte 62914560 (516 floats)
  uint2* ws_u2 = (uint2*)d_ws;
  float* wcomb = (float*)((char*)d_ws + 62914560u);

  comb_kernel<<<dim3(1), dim3(512), 0, stream>>>(W_lat, b_lat, W_out, b_out, wcomb);
  lstm_fused<<<dim3(256), dim3(512), 0, stream>>>(inputs_main, inputs_sfc, rnn1_mem, hx2, cx2,
      W_sfc1, b_sfc1, W_sfc2, b_sfc2, Wih1, Whh1, bih1, bhh1, Wih2, Whh2, bih2, bhh2,
      W_so, b_so, wcomb, ws_u2, out);
}